// Round 1
// baseline (119.720 us; speedup 1.0000x reference)
//
#include <hip/hip_runtime.h>

#define HH 512
#define WW 512
#define NB 4
#define RR 4
#define EPSF 1e-8f
#define PLANE (NB * HH * WW)   // 4,194,304 elements? no: 4*512*512 = 1,048,576 per... see below
// PLANE here = total pixels across batch = NB*HH*WW = 1,048,576? Actually 4*512*512 = 1,048,576.
// Each "plane" (one channel over all batches) = PLANE floats = 4 MB.

// ---------------- Kernel 1: products + horizontal box sum (13 channels) ----------------
__global__ __launch_bounds__(256) void k_h1(const float* __restrict__ y,
                                            const float* __restrict__ x,
                                            float* __restrict__ o) {
    int idx = blockIdx.x * 256 + threadIdx.x;          // 0 .. PLANE-1
    int j  = idx & (WW - 1);
    int ni = idx >> 9;                                  // n*HH + i
    int i  = ni & (HH - 1);
    int n  = ni >> 9;
    const float* yrow = y + (size_t)ni * WW;                       // y is (n,1,h,w)
    const float* x0r  = x + ((size_t)(n * 3 + 0) * HH + i) * WW;   // x is (n,3,h,w)
    const float* x1r  = x0r + (size_t)HH * WW;
    const float* x2r  = x1r + (size_t)HH * WW;

    int j0 = j - RR < 0 ? 0 : j - RR;
    int j1 = j + RR > WW - 1 ? WW - 1 : j + RR;

    float s[13];
#pragma unroll
    for (int p = 0; p < 13; ++p) s[p] = 0.0f;

    for (int jj = j0; jj <= j1; ++jj) {
        float yy = yrow[jj];
        float a = x0r[jj], b = x1r[jj], c = x2r[jj];
        s[0] += a;  s[1] += b;  s[2] += c;  s[3] += yy;
        s[4] += yy * a;  s[5] += yy * b;  s[6] += yy * c;
        s[7] += a * a;  s[8] += a * b;  s[9]  += a * c;
        s[10] += b * b; s[11] += b * c; s[12] += c * c;
    }
#pragma unroll
    for (int p = 0; p < 13; ++p) o[(size_t)p * PLANE + idx] = s[p];
}

// ---------------- Kernel 2: vertical box sum + covariance + 3x3 solve -> A,b ----------------
__global__ __launch_bounds__(256) void k_v1(const float* __restrict__ hs,
                                            float* __restrict__ ab) {
    int idx = blockIdx.x * 256 + threadIdx.x;
    int j  = idx & (WW - 1);
    int ni = idx >> 9;
    int i  = ni & (HH - 1);
    int n  = ni >> 9;

    int i0 = i - RR < 0 ? 0 : i - RR;
    int i1 = i + RR > HH - 1 ? HH - 1 : i + RR;

    float s[13];
#pragma unroll
    for (int p = 0; p < 13; ++p) s[p] = 0.0f;

    for (int ii = i0; ii <= i1; ++ii) {
        size_t base = ((size_t)n * HH + ii) * WW + j;
#pragma unroll
        for (int p = 0; p < 13; ++p) s[p] += hs[(size_t)p * PLANE + base];
    }

    int j0 = j - RR < 0 ? 0 : j - RR;
    int j1 = j + RR > WW - 1 ? WW - 1 : j + RR;
    float cnt  = (float)((i1 - i0 + 1) * (j1 - j0 + 1));
    float invn = 1.0f / cnt;

    float mx0 = s[0] * invn, mx1 = s[1] * invn, mx2 = s[2] * invn;
    float my  = s[3] * invn;

    float cy0 = s[4] * invn - my * mx0;
    float cy1 = s[5] * invn - my * mx1;
    float cy2 = s[6] * invn - my * mx2;

    float a00 = s[7]  * invn - mx0 * mx0 + EPSF;
    float a01 = s[8]  * invn - mx0 * mx1;
    float a02 = s[9]  * invn - mx0 * mx2;
    float a11 = s[10] * invn - mx1 * mx1 + EPSF;
    float a12 = s[11] * invn - mx1 * mx2;
    float a22 = s[12] * invn - mx2 * mx2 + EPSF;

    // symmetric 3x3 inverse via adjugate
    float c00 = a11 * a22 - a12 * a12;
    float c01 = a02 * a12 - a01 * a22;
    float c02 = a01 * a12 - a02 * a11;
    float det = a00 * c00 + a01 * c01 + a02 * c02;
    float id  = 1.0f / det;
    float i00 = c00 * id, i01 = c01 * id, i02 = c02 * id;
    float i11 = (a00 * a22 - a02 * a02) * id;
    float i12 = (a01 * a02 - a00 * a12) * id;
    float i22 = (a00 * a11 - a01 * a01) * id;

    float A0 = cy0 * i00 + cy1 * i01 + cy2 * i02;
    float A1 = cy0 * i01 + cy1 * i11 + cy2 * i12;
    float A2 = cy0 * i02 + cy1 * i12 + cy2 * i22;
    float bb = my - (A0 * mx0 + A1 * mx1 + A2 * mx2);

    ab[idx]                     = A0;
    ab[(size_t)PLANE + idx]     = A1;
    ab[(size_t)2 * PLANE + idx] = A2;
    ab[(size_t)3 * PLANE + idx] = bb;
}

// ---------------- Kernel 3: horizontal box sum of A,b (4 channels) ----------------
__global__ __launch_bounds__(256) void k_h2(const float* __restrict__ ab,
                                            float* __restrict__ o) {
    int idx = blockIdx.x * 256 + threadIdx.x;
    int j  = idx & (WW - 1);
    int rowbase = idx - j;

    int j0 = j - RR < 0 ? 0 : j - RR;
    int j1 = j + RR > WW - 1 ? WW - 1 : j + RR;

    float s0 = 0.f, s1 = 0.f, s2 = 0.f, s3 = 0.f;
    for (int jj = j0; jj <= j1; ++jj) {
        size_t base = (size_t)rowbase + jj;
        s0 += ab[base];
        s1 += ab[(size_t)PLANE + base];
        s2 += ab[(size_t)2 * PLANE + base];
        s3 += ab[(size_t)3 * PLANE + base];
    }
    o[idx]                     = s0;
    o[(size_t)PLANE + idx]     = s1;
    o[(size_t)2 * PLANE + idx] = s2;
    o[(size_t)3 * PLANE + idx] = s3;
}

// ---------------- Kernel 4: vertical box sum, /N, final combine ----------------
__global__ __launch_bounds__(256) void k_v2(const float* __restrict__ hs,
                                            const float* __restrict__ x,
                                            float* __restrict__ out) {
    int idx = blockIdx.x * 256 + threadIdx.x;
    int j  = idx & (WW - 1);
    int ni = idx >> 9;
    int i  = ni & (HH - 1);
    int n  = ni >> 9;

    int i0 = i - RR < 0 ? 0 : i - RR;
    int i1 = i + RR > HH - 1 ? HH - 1 : i + RR;

    float s0 = 0.f, s1 = 0.f, s2 = 0.f, s3 = 0.f;
    for (int ii = i0; ii <= i1; ++ii) {
        size_t base = ((size_t)n * HH + ii) * WW + j;
        s0 += hs[base];
        s1 += hs[(size_t)PLANE + base];
        s2 += hs[(size_t)2 * PLANE + base];
        s3 += hs[(size_t)3 * PLANE + base];
    }

    int j0 = j - RR < 0 ? 0 : j - RR;
    int j1 = j + RR > WW - 1 ? WW - 1 : j + RR;
    float invn = 1.0f / (float)((i1 - i0 + 1) * (j1 - j0 + 1));

    float x0 = x[((size_t)(n * 3 + 0) * HH + i) * WW + j];
    float x1 = x[((size_t)(n * 3 + 1) * HH + i) * WW + j];
    float x2 = x[((size_t)(n * 3 + 2) * HH + i) * WW + j];

    out[idx] = (s0 * x0 + s1 * x1 + s2 * x2 + s3) * invn;
}

extern "C" void kernel_launch(void* const* d_in, const int* in_sizes, int n_in,
                              void* d_out, int out_size, void* d_ws, size_t ws_size,
                              hipStream_t stream) {
    const float* y = (const float*)d_in[0];   // (4,1,512,512)
    const float* x = (const float*)d_in[1];   // (4,3,512,512)
    float* out = (float*)d_out;               // (4,1,512,512)

    float* wsf  = (float*)d_ws;
    float* buf1 = wsf;                           // 13 planes (52 MB) — h-sums of products
    float* buf2 = wsf + (size_t)13 * PLANE;      // 4 planes (16 MB) — A0,A1,A2,b
    float* buf3 = wsf;                           // 4 planes, aliases buf1 (dead by then)

    dim3 block(256);
    dim3 grid(PLANE / 256);

    k_h1<<<grid, block, 0, stream>>>(y, x, buf1);
    k_v1<<<grid, block, 0, stream>>>(buf1, buf2);
    k_h2<<<grid, block, 0, stream>>>(buf2, buf3);
    k_v2<<<grid, block, 0, stream>>>(buf3, x, out);
}

// Round 2
// 59.209 us; speedup vs baseline: 2.0220x; 2.0220x over previous
//
#include <hip/hip_runtime.h>

#define HH 512
#define WW 512
#define NB 4
#define RR 4
#define EPSF 1e-8f
#define PLANE (NB * HH * WW)     // 1,048,576 px total (all batches), 4 MB/plane
#define QPLANE (PLANE / 4)

// ---- horizontal window load: 12 aligned floats (3x float4), zero-padded at edges ----
#define LOADW(W, P) { \
    float4 qa = vlo ? *(const float4*)((P) + jb)     : make_float4(0.f,0.f,0.f,0.f); \
    float4 qb =       *(const float4*)((P) + j0); \
    float4 qc = vhi ? *(const float4*)((P) + j0 + 4) : make_float4(0.f,0.f,0.f,0.f); \
    W[0]=qa.x; W[1]=qa.y; W[2]=qa.z;  W[3]=qa.w; \
    W[4]=qb.x; W[5]=qb.y; W[6]=qb.z;  W[7]=qb.w; \
    W[8]=qc.x; W[9]=qc.y; W[10]=qc.z; W[11]=qc.w; }

// ---- horizontal box of 4 consecutive outputs via sliding sums, float4 store ----
#define BOX4(OUT, ch, PEXPR) { \
    float p[12]; \
    _Pragma("unroll") for (int k = 0; k < 12; ++k) { p[k] = (PEXPR); } \
    float s0 = ((p[0]+p[1])+(p[2]+p[3])) + ((p[4]+p[5])+(p[6]+p[7])) + p[8]; \
    float s1 = s0 - p[0] + p[9]; \
    float s2 = s1 - p[1] + p[10]; \
    float s3 = s2 - p[2] + p[11]; \
    *(float4*)((OUT) + (size_t)(ch) * PLANE + ((size_t)idx4 << 2)) = make_float4(s0, s1, s2, s3); }

// ================= Kernel 1: products + horizontal box (13 planes) =================
__global__ __launch_bounds__(256) void k_h1(const float* __restrict__ y,
                                            const float* __restrict__ x,
                                            float* __restrict__ o) {
    int idx4 = blockIdx.x * 256 + threadIdx.x;   // [0, QPLANE)
    int j0 = (idx4 & 127) << 2;                  // run start col (mult of 4)
    int ni = idx4 >> 7;                          // n*HH + i
    int i  = ni & (HH - 1);
    int n  = ni >> 9;

    const float* yr = y + (size_t)ni * WW;
    size_t xb = ((size_t)(n * 3) * HH + i) * WW;
    const float* ar = x + xb;
    const float* br = x + xb + (size_t)HH * WW;
    const float* cr = x + xb + (size_t)2 * HH * WW;

    int jb = j0 - 4;
    bool vlo = (j0 >= 4);
    bool vhi = (j0 < 508);

    float aw[12], bw[12], cw[12], yw[12];
    LOADW(aw, ar); LOADW(bw, br); LOADW(cw, cr); LOADW(yw, yr);

    BOX4(o, 0,  aw[k]);
    BOX4(o, 1,  bw[k]);
    BOX4(o, 2,  cw[k]);
    BOX4(o, 3,  yw[k]);
    BOX4(o, 4,  yw[k] * aw[k]);
    BOX4(o, 5,  yw[k] * bw[k]);
    BOX4(o, 6,  yw[k] * cw[k]);
    BOX4(o, 7,  aw[k] * aw[k]);
    BOX4(o, 8,  aw[k] * bw[k]);
    BOX4(o, 9,  aw[k] * cw[k]);
    BOX4(o, 10, bw[k] * bw[k]);
    BOX4(o, 11, bw[k] * cw[k]);
    BOX4(o, 12, cw[k] * cw[k]);
}

// ================= Kernel 2: vertical box (streamed, 4 rows/thread) + solve =================
__global__ __launch_bounds__(256) void k_v1(const float* __restrict__ hs,
                                            float* __restrict__ ab) {
    // XCD-contiguous swizzle: each XCD gets a contiguous chunk of row-groups
    int b = blockIdx.x;
    int sb = (b & 7) * ((int)gridDim.x >> 3) + (b >> 3);
    int idx4 = sb * 256 + threadIdx.x;           // [0, QPLANE)
    int col = idx4 & (WW - 1);
    int g   = idx4 >> 9;                         // row-group [0, NB*HH/4)
    int ib  = (g & 127) << 2;                    // base output row
    int n   = g >> 7;

    float acc0[13], acc1[13], acc2[13], acc3[13];
#pragma unroll
    for (int ch = 0; ch < 13; ++ch) { acc0[ch] = 0.f; acc1[ch] = 0.f; acc2[ch] = 0.f; acc3[ch] = 0.f; }

#pragma unroll
    for (int r = 0; r < 12; ++r) {
        int row = ib - 4 + r;
        if (row >= 0 && row < HH) {              // wave-uniform
            size_t base = ((size_t)n * HH + row) * WW + col;
            float h[13];
#pragma unroll
            for (int ch = 0; ch < 13; ++ch) h[ch] = hs[(size_t)ch * PLANE + base];
#pragma unroll
            for (int ch = 0; ch < 13; ++ch) {
                if (r <= 8)            acc0[ch] += h[ch];
                if (r >= 1 && r <= 9)  acc1[ch] += h[ch];
                if (r >= 2 && r <= 10) acc2[ch] += h[ch];
                if (r >= 3)            acc3[ch] += h[ch];
            }
        }
    }

#define SOLVET(S, I) { \
    int i0r = (I) - RR < 0 ? 0 : (I) - RR; \
    int i1r = (I) + RR > HH - 1 ? HH - 1 : (I) + RR; \
    int j0r = col - RR < 0 ? 0 : col - RR; \
    int j1r = col + RR > WW - 1 ? WW - 1 : col + RR; \
    float invn = 1.0f / (float)((i1r - i0r + 1) * (j1r - j0r + 1)); \
    float mx0 = S[0]*invn, mx1 = S[1]*invn, mx2 = S[2]*invn, my = S[3]*invn; \
    float cy0 = S[4]*invn - my*mx0, cy1 = S[5]*invn - my*mx1, cy2 = S[6]*invn - my*mx2; \
    float a00 = S[7]*invn  - mx0*mx0 + EPSF; \
    float a01 = S[8]*invn  - mx0*mx1; \
    float a02 = S[9]*invn  - mx0*mx2; \
    float a11 = S[10]*invn - mx1*mx1 + EPSF; \
    float a12 = S[11]*invn - mx1*mx2; \
    float a22 = S[12]*invn - mx2*mx2 + EPSF; \
    float c00 = a11*a22 - a12*a12, c01 = a02*a12 - a01*a22, c02 = a01*a12 - a02*a11; \
    float det = a00*c00 + a01*c01 + a02*c02; \
    float id  = 1.0f / det; \
    float i00 = c00*id, i01 = c01*id, i02 = c02*id; \
    float i11 = (a00*a22 - a02*a02)*id; \
    float i12 = (a01*a02 - a00*a12)*id; \
    float i22 = (a00*a11 - a01*a01)*id; \
    float A0 = cy0*i00 + cy1*i01 + cy2*i02; \
    float A1 = cy0*i01 + cy1*i11 + cy2*i12; \
    float A2 = cy0*i02 + cy1*i12 + cy2*i22; \
    float bb = my - (A0*mx0 + A1*mx1 + A2*mx2); \
    size_t px = ((size_t)n * HH + (I)) * WW + col; \
    ab[px] = A0; ab[(size_t)PLANE + px] = A1; \
    ab[(size_t)2 * PLANE + px] = A2; ab[(size_t)3 * PLANE + px] = bb; }

    SOLVET(acc0, ib + 0);
    SOLVET(acc1, ib + 1);
    SOLVET(acc2, ib + 2);
    SOLVET(acc3, ib + 3);
#undef SOLVET
}

// ================= Kernel 3: horizontal box of A,b (4 planes) =================
__global__ __launch_bounds__(256) void k_h2(const float* __restrict__ ab,
                                            float* __restrict__ o) {
    int idx4 = blockIdx.x * 256 + threadIdx.x;
    int j0 = (idx4 & 127) << 2;
    int ni = idx4 >> 7;

    const float* r0 = ab + (size_t)ni * WW;
    const float* r1 = r0 + (size_t)PLANE;
    const float* r2 = r0 + (size_t)2 * PLANE;
    const float* r3 = r0 + (size_t)3 * PLANE;

    int jb = j0 - 4;
    bool vlo = (j0 >= 4);
    bool vhi = (j0 < 508);

    float w0[12], w1[12], w2[12], w3[12];
    LOADW(w0, r0); LOADW(w1, r1); LOADW(w2, r2); LOADW(w3, r3);

    BOX4(o, 0, w0[k]);
    BOX4(o, 1, w1[k]);
    BOX4(o, 2, w2[k]);
    BOX4(o, 3, w3[k]);
}

// ================= Kernel 4: vertical box (streamed) + /N + combine =================
__global__ __launch_bounds__(256) void k_v2(const float* __restrict__ hs,
                                            const float* __restrict__ x,
                                            float* __restrict__ out) {
    int b = blockIdx.x;
    int sb = (b & 7) * ((int)gridDim.x >> 3) + (b >> 3);
    int idx4 = sb * 256 + threadIdx.x;
    int col = idx4 & (WW - 1);
    int g   = idx4 >> 9;
    int ib  = (g & 127) << 2;
    int n   = g >> 7;

    float acc0[4], acc1[4], acc2[4], acc3[4];
#pragma unroll
    for (int ch = 0; ch < 4; ++ch) { acc0[ch] = 0.f; acc1[ch] = 0.f; acc2[ch] = 0.f; acc3[ch] = 0.f; }

#pragma unroll
    for (int r = 0; r < 12; ++r) {
        int row = ib - 4 + r;
        if (row >= 0 && row < HH) {
            size_t base = ((size_t)n * HH + row) * WW + col;
            float h[4];
#pragma unroll
            for (int ch = 0; ch < 4; ++ch) h[ch] = hs[(size_t)ch * PLANE + base];
#pragma unroll
            for (int ch = 0; ch < 4; ++ch) {
                if (r <= 8)            acc0[ch] += h[ch];
                if (r >= 1 && r <= 9)  acc1[ch] += h[ch];
                if (r >= 2 && r <= 10) acc2[ch] += h[ch];
                if (r >= 3)            acc3[ch] += h[ch];
            }
        }
    }

#define FINT(S, I) { \
    int i0r = (I) - RR < 0 ? 0 : (I) - RR; \
    int i1r = (I) + RR > HH - 1 ? HH - 1 : (I) + RR; \
    int j0r = col - RR < 0 ? 0 : col - RR; \
    int j1r = col + RR > WW - 1 ? WW - 1 : col + RR; \
    float invn = 1.0f / (float)((i1r - i0r + 1) * (j1r - j0r + 1)); \
    size_t px = ((size_t)n * HH + (I)) * WW + col; \
    size_t xpx = ((size_t)(n * 3) * HH + (I)) * WW + col; \
    float x0 = x[xpx]; \
    float x1 = x[xpx + (size_t)HH * WW]; \
    float x2 = x[xpx + (size_t)2 * HH * WW]; \
    out[px] = (S[0] * x0 + S[1] * x1 + S[2] * x2 + S[3]) * invn; }

    FINT(acc0, ib + 0);
    FINT(acc1, ib + 1);
    FINT(acc2, ib + 2);
    FINT(acc3, ib + 3);
#undef FINT
}

extern "C" void kernel_launch(void* const* d_in, const int* in_sizes, int n_in,
                              void* d_out, int out_size, void* d_ws, size_t ws_size,
                              hipStream_t stream) {
    const float* y = (const float*)d_in[0];   // (4,1,512,512)
    const float* x = (const float*)d_in[1];   // (4,3,512,512)
    float* out = (float*)d_out;               // (4,1,512,512)

    float* wsf  = (float*)d_ws;
    float* buf1 = wsf;                           // 13 planes (52 MB) — h-sums of products
    float* buf2 = wsf + (size_t)13 * PLANE;      // 4 planes (16 MB) — A0,A1,A2,b
    float* buf3 = wsf;                           // 4 planes, aliases buf1 (dead by then)

    dim3 block(256);
    dim3 grid(QPLANE / 256);                     // 1024 blocks

    k_h1<<<grid, block, 0, stream>>>(y, x, buf1);
    k_v1<<<grid, block, 0, stream>>>(buf1, buf2);
    k_h2<<<grid, block, 0, stream>>>(buf2, buf3);
    k_v2<<<grid, block, 0, stream>>>(buf3, x, out);
}

// Round 3
// 44.063 us; speedup vs baseline: 2.7170x; 1.3437x over previous
//
#include <hip/hip_runtime.h>

#define HH 512
#define WW 512
#define NB 4
#define RR 4
#define EPSF 1e-8f

// F1: 64 wide x 16 high output tile, 24 LDS rows (4-row halo each side)
#define F1_LR 24
// F2: 64 wide x 32 high output tile, 40 LDS rows
#define F2_LR 40

__device__ __forceinline__ float4 f4add(float4 a, float4 b) {
    return make_float4(a.x + b.x, a.y + b.y, a.z + b.z, a.w + b.w);
}
__device__ __forceinline__ float4 f4sub(float4 a, float4 b) {
    return make_float4(a.x - b.x, a.y - b.y, a.z - b.z, a.w - b.w);
}

// load 12-float horizontal window (3x aligned float4), zero-padded outside image
#define LOADW(W, P) { \
    float4 qa = vlo ? *(const float4*)((P) + gj0 - 4) : make_float4(0.f,0.f,0.f,0.f); \
    float4 qb =       *(const float4*)((P) + gj0); \
    float4 qc = vhi ? *(const float4*)((P) + gj0 + 4) : make_float4(0.f,0.f,0.f,0.f); \
    W[0]=qa.x; W[1]=qa.y; W[2]=qa.z;  W[3]=qa.w; \
    W[4]=qb.x; W[5]=qb.y; W[6]=qb.z;  W[7]=qb.w; \
    W[8]=qc.x; W[9]=qc.y; W[10]=qc.z; W[11]=qc.w; }

// horizontal box of 4 consecutive cols via sliding sums -> LDS
#define HBOXS(ch, EXPR) { \
    float p[12]; \
    _Pragma("unroll") for (int k = 0; k < 12; ++k) p[k] = (EXPR); \
    float t0 = ((p[0]+p[1])+(p[2]+p[3])) + ((p[4]+p[5])+(p[6]+p[7])) + p[8]; \
    float t1 = t0 - p[0] + p[9]; \
    float t2 = t1 - p[1] + p[10]; \
    float t3 = t2 - p[2] + p[11]; \
    *(float4*)&lds[ch][r][q4] = make_float4(t0, t1, t2, t3); }

// ============ Kernel F1: y,x -> A,b (fused products + hbox + vbox + solve) ============
__global__ __launch_bounds__(256) void k_f1(const float* __restrict__ y,
                                            const float* __restrict__ x,
                                            float* __restrict__ ab) {
    __shared__ float lds[13][F1_LR][64];
    const int bx  = blockIdx.x;
    const int tj  = (bx & 7) << 6;          // tile col start
    const int ti  = ((bx >> 3) & 31) << 4;  // tile row start
    const int n   = bx >> 8;
    const int tid = threadIdx.x;

    const size_t plane = (size_t)HH * WW;
    const float* yp = y + (size_t)n * plane;
    const float* xp = x + (size_t)(3 * n) * plane;

    // ---- stage 1: h-sums of 13 product channels for 24 rows x 64 cols ----
    for (int task = tid; task < F1_LR * 16; task += 256) {
        const int r   = task >> 4;          // 0..23
        const int q4  = (task & 15) << 2;   // 0,4,..,60
        const int gr  = ti - 4 + r;
        const int gj0 = tj + q4;
        if (gr >= 0 && gr < HH) {
            const float* yr = yp + (size_t)gr * WW;
            const float* ar = xp + (size_t)gr * WW;
            const float* br = ar + plane;
            const float* cr = br + plane;
            const bool vlo = gj0 >= 4;
            const bool vhi = gj0 < WW - 4;
            float aw[12], bw[12], cw[12], yw[12];
            LOADW(aw, ar); LOADW(bw, br); LOADW(cw, cr); LOADW(yw, yr);
            HBOXS(0,  aw[k]);
            HBOXS(1,  bw[k]);
            HBOXS(2,  cw[k]);
            HBOXS(3,  yw[k]);
            HBOXS(4,  yw[k] * aw[k]);
            HBOXS(5,  yw[k] * bw[k]);
            HBOXS(6,  yw[k] * cw[k]);
            HBOXS(7,  aw[k] * aw[k]);
            HBOXS(8,  aw[k] * bw[k]);
            HBOXS(9,  aw[k] * cw[k]);
            HBOXS(10, bw[k] * bw[k]);
            HBOXS(11, bw[k] * cw[k]);
            HBOXS(12, cw[k] * cw[k]);
        } else {
            const float4 z = make_float4(0.f, 0.f, 0.f, 0.f);
#pragma unroll
            for (int ch = 0; ch < 13; ++ch) *(float4*)&lds[ch][r][q4] = z;
        }
    }
    __syncthreads();

    // ---- stage 2: vertical 9-sum (sliding) + 3x3 solve, 4 rows/thread ----
    const int col = tid & 63;
    const int rb  = (tid >> 6) << 2;        // 0,4,8,12
    float s[13][4];
#pragma unroll
    for (int ch = 0; ch < 13; ++ch) {
        float v[12];
#pragma unroll
        for (int k = 0; k < 12; ++k) v[k] = lds[ch][rb + k][col];
        float t0 = ((v[0]+v[1])+(v[2]+v[3])) + ((v[4]+v[5])+(v[6]+v[7])) + v[8];
        s[ch][0] = t0;
        s[ch][1] = t0        - v[0] + v[9];
        s[ch][2] = s[ch][1]  - v[1] + v[10];
        s[ch][3] = s[ch][2]  - v[2] + v[11];
    }

    const int gj  = tj + col;
    const int j0r = gj - RR < 0 ? 0 : gj - RR;
    const int j1r = gj + RR > WW - 1 ? WW - 1 : gj + RR;
    const float wcnt = (float)(j1r - j0r + 1);

    float4* abp = (float4*)ab + (size_t)n * plane;

#pragma unroll
    for (int k = 0; k < 4; ++k) {
        const int i   = ti + rb + k;
        const int i0r = i - RR < 0 ? 0 : i - RR;
        const int i1r = i + RR > HH - 1 ? HH - 1 : i + RR;
        const float invn = 1.0f / ((float)(i1r - i0r + 1) * wcnt);

        float mx0 = s[0][k]*invn, mx1 = s[1][k]*invn, mx2 = s[2][k]*invn, my = s[3][k]*invn;
        float cy0 = s[4][k]*invn - my*mx0;
        float cy1 = s[5][k]*invn - my*mx1;
        float cy2 = s[6][k]*invn - my*mx2;
        float a00 = s[7][k]*invn  - mx0*mx0 + EPSF;
        float a01 = s[8][k]*invn  - mx0*mx1;
        float a02 = s[9][k]*invn  - mx0*mx2;
        float a11 = s[10][k]*invn - mx1*mx1 + EPSF;
        float a12 = s[11][k]*invn - mx1*mx2;
        float a22 = s[12][k]*invn - mx2*mx2 + EPSF;

        float c00 = a11*a22 - a12*a12;
        float c01 = a02*a12 - a01*a22;
        float c02 = a01*a12 - a02*a11;
        float det = a00*c00 + a01*c01 + a02*c02;
        float id  = 1.0f / det;
        float i00 = c00*id, i01 = c01*id, i02 = c02*id;
        float i11 = (a00*a22 - a02*a02)*id;
        float i12 = (a01*a02 - a00*a12)*id;
        float i22 = (a00*a11 - a01*a01)*id;

        float A0 = cy0*i00 + cy1*i01 + cy2*i02;
        float A1 = cy0*i01 + cy1*i11 + cy2*i12;
        float A2 = cy0*i02 + cy1*i12 + cy2*i22;
        float bb = my - (A0*mx0 + A1*mx1 + A2*mx2);

        abp[(size_t)i * WW + gj] = make_float4(A0, A1, A2, bb);
    }
}

// ============ Kernel F2: A,b,x -> out (fused hbox + vbox + combine) ============
__global__ __launch_bounds__(256) void k_f2(const float* __restrict__ ab,
                                            const float* __restrict__ x,
                                            float* __restrict__ out) {
    __shared__ float4 lds[F2_LR][64];
    const int bx  = blockIdx.x;
    const int tj  = (bx & 7) << 6;
    const int ti  = ((bx >> 3) & 15) << 5;
    const int n   = bx >> 7;
    const int tid = threadIdx.x;

    const size_t plane = (size_t)HH * WW;
    const float4* abp = (const float4*)ab + (size_t)n * plane;

    // ---- stage 1: h-box of interleaved A,b into LDS (40 rows) ----
    for (int task = tid; task < F2_LR * 16; task += 256) {
        const int r   = task >> 4;
        const int q4  = (task & 15) << 2;
        const int gr  = ti - 4 + r;
        const int gj0 = tj + q4;
        if (gr >= 0 && gr < HH) {
            const float4* rr = abp + (size_t)gr * WW;
            const bool vlo = gj0 >= 4;
            const bool vhi = gj0 < WW - 4;
            const float4 z = make_float4(0.f, 0.f, 0.f, 0.f);
            float4 w[12];
#pragma unroll
            for (int k = 0; k < 4; ++k) w[k]     = vlo ? rr[gj0 - 4 + k] : z;
#pragma unroll
            for (int k = 0; k < 4; ++k) w[4 + k] = rr[gj0 + k];
#pragma unroll
            for (int k = 0; k < 4; ++k) w[8 + k] = vhi ? rr[gj0 + 4 + k] : z;

            float4 t0 = f4add(f4add(f4add(f4add(w[0], w[1]), f4add(w[2], w[3])),
                                    f4add(f4add(w[4], w[5]), f4add(w[6], w[7]))), w[8]);
            float4 t1 = f4add(f4sub(t0, w[0]), w[9]);
            float4 t2 = f4add(f4sub(t1, w[1]), w[10]);
            float4 t3 = f4add(f4sub(t2, w[2]), w[11]);
            lds[r][q4 + 0] = t0;
            lds[r][q4 + 1] = t1;
            lds[r][q4 + 2] = t2;
            lds[r][q4 + 3] = t3;
        } else {
            const float4 z = make_float4(0.f, 0.f, 0.f, 0.f);
            lds[r][q4 + 0] = z; lds[r][q4 + 1] = z;
            lds[r][q4 + 2] = z; lds[r][q4 + 3] = z;
        }
    }
    __syncthreads();

    // ---- stage 2: vertical 9-sum (sliding) + combine, 8 rows/thread ----
    const int col = tid & 63;
    const int rb  = (tid >> 6) << 3;        // 0,8,16,24
    const int gj  = tj + col;
    const int j0r = gj - RR < 0 ? 0 : gj - RR;
    const int j1r = gj + RR > WW - 1 ? WW - 1 : gj + RR;
    const float wcnt = (float)(j1r - j0r + 1);

    float4 acc = lds[rb][col];
#pragma unroll
    for (int k = 1; k < 9; ++k) acc = f4add(acc, lds[rb + k][col]);

    const float* xp = x + (size_t)(3 * n) * plane;
    float* op = out + (size_t)n * plane;

#pragma unroll
    for (int k = 0; k < 8; ++k) {
        const int i   = ti + rb + k;
        const int i0r = i - RR < 0 ? 0 : i - RR;
        const int i1r = i + RR > HH - 1 ? HH - 1 : i + RR;
        const float invn = 1.0f / ((float)(i1r - i0r + 1) * wcnt);

        const size_t px = (size_t)i * WW + gj;
        const float x0 = xp[px];
        const float x1 = xp[px + plane];
        const float x2 = xp[px + 2 * plane];
        op[px] = (acc.x * x0 + acc.y * x1 + acc.z * x2 + acc.w) * invn;

        if (k < 7) acc = f4add(f4sub(acc, lds[rb + k][col]), lds[rb + k + 9][col]);
    }
}

extern "C" void kernel_launch(void* const* d_in, const int* in_sizes, int n_in,
                              void* d_out, int out_size, void* d_ws, size_t ws_size,
                              hipStream_t stream) {
    const float* y = (const float*)d_in[0];   // (4,1,512,512)
    const float* x = (const float*)d_in[1];   // (4,3,512,512)
    float* out = (float*)d_out;               // (4,1,512,512)

    float* ab = (float*)d_ws;                 // (4,512,512,4) interleaved A0,A1,A2,b = 16 MB

    k_f1<<<dim3(8 * 32 * NB), dim3(256), 0, stream>>>(y, x, ab);
    k_f2<<<dim3(8 * 16 * NB), dim3(256), 0, stream>>>(ab, x, out);
}